// Round 5
// baseline (514.459 us; speedup 1.0000x reference)
//
#include <hip/hip_runtime.h>
#include <hip/hip_bf16.h>

#define H 128
#define BK 64
#define LDSTR 72   // LDS row stride (f16 elems): 144B, 16B-aligned rows

#define EPB 8192        // edges per block, coarse passes
#define BUCK_BITS 8
#define BUCK 256        // nodes per bucket
#define CHN 25000       // nodes per deg-out chunk (16-bit packed counters, 50KB LDS)
#define SLOTS 12500
#define SLA 24          // edge slices per chunk, type A
#define SLB 16

typedef _Float16 f16;
typedef unsigned int u32;
typedef __attribute__((ext_vector_type(8))) _Float16 f16x8;
typedef __attribute__((ext_vector_type(4))) _Float16 f16x4;
typedef __attribute__((ext_vector_type(2))) _Float16 f16x2;
typedef __attribute__((ext_vector_type(4))) float floatx4;

static inline __host__ int ceil_div(int a, int b) { return (a + b - 1) / b; }

// ======== prep K1: coarse dst-hist | src-deg hist | weight transpose ========
__global__ __launch_bounds__(256) void prepK1(
    const int* __restrict__ dA, int* __restrict__ chA, int EA, int nblkA, int nbinsA,
    const int* __restrict__ dB, int* __restrict__ chB, int EB, int nblkB, int nbinsB,
    const int* __restrict__ sA, u32* __restrict__ pA, int NA,
    const int* __restrict__ sB, u32* __restrict__ pB, int NB,
    const float* __restrict__ Wa0, f16* ta0, const float* __restrict__ Wa1, f16* ta1,
    const float* __restrict__ Wb0, f16* tb0, const float* __restrict__ Wb1, f16* tb1, int DA) {
    __shared__ u32 shl[SLOTS];
    int bid = blockIdx.x;
    int t = threadIdx.x;
    int p1n = nblkA + nblkB;
    int nchA = (NA + CHN - 1) / CHN, nchB = (NB + CHN - 1) / CHN;
    int hn = nchA * SLA + nchB * SLB;
    if (bid < p1n) {
        int* bins = (int*)shl;
        const int* dst; int* ch; int E, nblk, nbins, blk;
        if (bid < nblkA) { dst = dA; ch = chA; E = EA; nblk = nblkA; nbins = nbinsA; blk = bid; }
        else { dst = dB; ch = chB; E = EB; nblk = nblkB; nbins = nbinsB; blk = bid - nblkA; }
        bins[t] = 0;
        __syncthreads();
        int e0 = blk * EPB, e1 = min(E, e0 + EPB);
        for (int e = e0 + t; e < e1; e += 256) atomicAdd(&bins[dst[e] >> BUCK_BITS], 1);
        __syncthreads();
        for (int b = t; b < nbins; b += 256) ch[b * nblk + blk] = bins[b];
    } else if (bid < p1n + hn) {
        int b2 = bid - p1n;
        const int* src; u32* part; int E, sl, chunk, g;
        if (b2 < nchA * SLA) { src = sA; part = pA; E = EA; sl = SLA; chunk = b2 / SLA; g = b2 % SLA; }
        else { b2 -= nchA * SLA; src = sB; part = pB; E = EB; sl = SLB; chunk = b2 / SLB; g = b2 % SLB; }
        for (int i = t; i < SLOTS; i += 256) shl[i] = 0;
        __syncthreads();
        int lo = chunk * CHN;
        int per = (E + sl - 1) / sl;
        int e0 = g * per, e1 = min(E, e0 + per);
        for (int e = e0 + t; e < e1; e += 256) {
            int s = src[e] - lo;
            if ((unsigned)s < (unsigned)CHN) atomicAdd(&shl[s >> 1], 1u << ((s & 1) << 4));
        }
        __syncthreads();
        u32* dp = part + (size_t)(chunk * sl + g) * SLOTS;
        for (int i = t; i < SLOTS; i += 256) dp[i] = shl[i];
    } else {
        int b2 = bid - p1n - hn;           // weight transpose: 2 k-rows per block
        int k2 = b2 * 2 + (t >> 7);
        const float* W; f16* T; int D, k;
        if (k2 < DA) { W = Wa0; T = ta0; D = DA; k = k2; }
        else if (k2 < DA + H) { W = Wa1; T = ta1; D = H; k = k2 - DA; }
        else if (k2 < DA + 2 * H) { W = Wb0; T = tb0; D = H; k = k2 - DA - H; }
        else { W = Wb1; T = tb1; D = H; k = k2 - DA - 2 * H; }
        int c = t & 127;
        T[(size_t)c * D + k] = (f16)W[(size_t)k * H + c];
    }
}

// ======== prep K2: scan of (bucket x block) matrix | deg-out reduce ========
__global__ __launch_bounds__(256) void prepK2(
    int* chA, int LA, int* bbA, int nbinsA, int nblkA, int EA, int* rpA, int NA,
    int* chB, int LB, int* bbB, int nbinsB, int nblkB, int EB, int* rpB, int NB,
    const u32* __restrict__ pA, float* __restrict__ nsA,
    const u32* __restrict__ pB, float* __restrict__ nsB) {
    __shared__ int sh[256];
    int bid = blockIdx.x, t = threadIdx.x;
    if (bid < 2) {
        int* ch; int L; int* bb; int nbins, nblk, E; int* rp; int N;
        if (bid == 0) { ch = chA; L = LA; bb = bbA; nbins = nbinsA; nblk = nblkA; E = EA; rp = rpA; N = NA; }
        else { ch = chB; L = LB; bb = bbB; nbins = nbinsB; nblk = nblkB; E = EB; rp = rpB; N = NB; }
        int per = (L + 255) >> 8;
        int lo = t * per, hi = min(lo + per, L);
        int s = 0;
        for (int i = lo; i < hi; i++) s += ch[i];
        sh[t] = s;
        __syncthreads();
        for (int off = 1; off < 256; off <<= 1) {
            int x = (t >= off) ? sh[t - off] : 0;
            __syncthreads();
            sh[t] += x;
            __syncthreads();
        }
        int run = sh[t] - s;
        for (int i = lo; i < hi; i++) { int v = ch[i]; ch[i] = run; run += v; }
        __syncthreads();
        for (int b = t; b <= nbins; b += 256) bb[b] = (b < nbins) ? ch[b * nblk] : E;
        if (t == 0) rp[N] = E;
    } else {
        int i = (bid - 2) * 256 + t;
        const u32* part; float* ns; int sl, idx;
        if (i < NA) { part = pA; ns = nsA; sl = SLA; idx = i; }
        else if (i < NA + NB) { part = pB; ns = nsB; sl = SLB; idx = i - NA; }
        else return;
        int chunk = idx / CHN, local = idx % CHN;
        int slot = local >> 1, shf = (local & 1) << 4;
        u32 sum = 0;
        const u32* base = part + (size_t)chunk * sl * SLOTS + slot;
        for (int g = 0; g < sl; g++) sum += base[(size_t)g * SLOTS];
        int deg = (int)((sum >> shf) & 0xFFFFu);
        ns[idx] = rsqrtf((float)(deg + 1));
    }
}

// ======== P3: scatter edges to bucket-ordered array (plain stores) ========
__global__ __launch_bounds__(256) void p3K(
    const int* __restrict__ sA, const int* __restrict__ dA, const int* __restrict__ chA,
    u32* __restrict__ binA, int EA, int nblkA, int nbinsA,
    const int* __restrict__ sB, const int* __restrict__ dB, const int* __restrict__ chB,
    u32* __restrict__ binB, int EB, int nblkB, int nbinsB) {
    __shared__ int bins[BUCK];
    __shared__ int off[BUCK];
    const int *src, *dst; const int* ch; u32* bin; int E, nblk, nbins, blk;
    if ((int)blockIdx.x < nblkA) {
        src = sA; dst = dA; ch = chA; bin = binA; E = EA; nblk = nblkA; nbins = nbinsA; blk = blockIdx.x;
    } else {
        src = sB; dst = dB; ch = chB; bin = binB; E = EB; nblk = nblkB; nbins = nbinsB; blk = blockIdx.x - nblkA;
    }
    int t = threadIdx.x;
    bins[t] = 0;
    if (t < nbins) off[t] = ch[t * nblk + blk];
    __syncthreads();
    int e0 = blk * EPB, e1 = min(E, e0 + EPB);
    for (int e = e0 + t; e < e1; e += 256) {
        int d = dst[e], s = src[e];
        int b = d >> BUCK_BITS;
        int r = atomicAdd(&bins[b], 1);
        bin[off[b] + r] = (u32)s | ((u32)(d & (BUCK - 1)) << 16);
    }
}

// ======== P4: per-bucket fine pass -> norm_d, rowptr, esrc ========
__global__ __launch_bounds__(256) void p4K(
    const u32* __restrict__ binA, const int* __restrict__ bbA, int nbinsA,
    int* __restrict__ rpA, float* __restrict__ ndA, int* __restrict__ esA, int NA,
    const u32* __restrict__ binB, const int* __restrict__ bbB, int nbinsB,
    int* __restrict__ rpB, float* __restrict__ ndB, int* __restrict__ esB, int NB) {
    __shared__ int cnt[BUCK], pos[BUCK], fill[BUCK];
    const u32* bin; const int* bb; int* rp; float* nd; int* es; int N, blk;
    if ((int)blockIdx.x < nbinsA) {
        bin = binA; bb = bbA; rp = rpA; nd = ndA; es = esA; N = NA; blk = blockIdx.x;
    } else {
        bin = binB; bb = bbB; rp = rpB; nd = ndB; es = esB; N = NB; blk = blockIdx.x - nbinsA;
    }
    int t = threadIdx.x;
    int e0 = bb[blk], e1 = bb[blk + 1];
    cnt[t] = 0; fill[t] = 0;
    __syncthreads();
    for (int e = e0 + t; e < e1; e += 256) atomicAdd(&cnt[(bin[e] >> 16) & 255], 1);
    __syncthreads();
    int c = cnt[t];
    int node = (blk << BUCK_BITS) + t;
    if (node < N) nd[node] = rsqrtf((float)(c + 1));
    pos[t] = c;
    __syncthreads();
    for (int off = 1; off < 256; off <<= 1) {
        int x = (t >= off) ? pos[t - off] : 0;
        __syncthreads();
        pos[t] += x;
        __syncthreads();
    }
    int start = e0 + pos[t] - c;
    pos[t] = start;
    if (node < N) rp[node] = start;
    __syncthreads();
    for (int e = e0 + t; e < e1; e += 256) {
        u32 w = bin[e];
        int i = (w >> 16) & 255;
        int r = atomicAdd(&fill[i], 1);
        es[pos[i] + r] = (int)(w & 0xFFFFu);
    }
}

// ======== MFMA GEMM (f16, merged A+B): Yplanes = f16( (X*ns) @ W ) ========
// Y stored as 4 planes of 32 dims: Y[p*N*32 + node*32 + dim_in_plane]
__global__ __launch_bounds__(256) void gemmF(
    const float* __restrict__ X32A, const f16* __restrict__ X16A, const f16* __restrict__ WtA,
    const float* __restrict__ nsA, f16* __restrict__ YA, int NA, int DA, int nblkA,
    const float* __restrict__ X32B, const f16* __restrict__ X16B, const f16* __restrict__ WtB,
    const float* __restrict__ nsB, f16* __restrict__ YB, int NB, int DB, int xf16) {
    const float* X32; const f16* X16; const f16* Wt; const float* ns; f16* Y; int N, D, bid;
    if ((int)blockIdx.x < nblkA) {
        X32 = X32A; X16 = X16A; Wt = WtA; ns = nsA; Y = YA; N = NA; D = DA; bid = blockIdx.x;
    } else {
        X32 = X32B; X16 = X16B; Wt = WtB; ns = nsB; Y = YB; N = NB; D = DB; bid = blockIdx.x - nblkA;
    }
    __shared__ f16 Xs[64 * LDSTR];
    __shared__ f16 Ws[128 * LDSTR];
    int t = threadIdx.x;
    int wv = t >> 6, lane = t & 63;
    int m = lane & 15, q = lane >> 4;
    int rowbase = bid * 64;

    floatx4 acc[8];
#pragma unroll
    for (int c = 0; c < 8; c++) acc[c] = (floatx4)(0.f);

    for (int k0 = 0; k0 < D; k0 += BK) {
        __syncthreads();
        if (xf16) {   // stage pre-scaled f16 X: plain 16B copies
            int kq = (t & 7) * 8;
            int r0 = t >> 3;
#pragma unroll
            for (int i = 0; i < 2; i++) {
                int r = r0 + i * 32;
                int grow = rowbase + r;
                f16x8 v = (f16x8)(f16)0;
                if (grow < N) v = *(const f16x8*)(X16 + (size_t)grow * D + k0 + kq);
                *(f16x8*)&Xs[r * LDSTR + kq] = v;
            }
        } else {      // stage fp32 X: fold norm_s, convert to f16
            int kq = (t & 15) * 4;
#pragma unroll
            for (int i = 0; i < 4; i++) {
                int r = (t >> 4) + i * 16;
                int grow = rowbase + r;
                float4 v = make_float4(0.f, 0.f, 0.f, 0.f);
                float nv = 0.f;
                if (grow < N) {
                    v = *(const float4*)(X32 + (size_t)grow * D + k0 + kq);
                    nv = ns[grow];
                }
                f16x4 hv;
                hv[0] = (f16)(v.x * nv); hv[1] = (f16)(v.y * nv);
                hv[2] = (f16)(v.z * nv); hv[3] = (f16)(v.w * nv);
                *(f16x4*)&Xs[r * LDSTR + kq] = hv;
            }
        }
        {   // stage W chunk: 128 c x 64 k
            int ks = (t & 7) * 8;
            int rb = t >> 3;
#pragma unroll
            for (int i = 0; i < 4; i++) {
                int c = rb + i * 32;
                *(f16x8*)&Ws[c * LDSTR + ks] = *(const f16x8*)&Wt[(size_t)c * D + k0 + ks];
            }
        }
        __syncthreads();
#pragma unroll
        for (int ks = 0; ks < BK; ks += 32) {
            f16x8 a = *(const f16x8*)&Xs[(wv * 16 + m) * LDSTR + ks + q * 8];
#pragma unroll
            for (int c = 0; c < 8; c++) {
                f16x8 b = *(const f16x8*)&Ws[(c * 16 + m) * LDSTR + ks + q * 8];
                acc[c] = __builtin_amdgcn_mfma_f32_16x16x32_f16(a, b, acc[c], 0, 0, 0);
            }
        }
    }
    // D layout col=lane&15, row=(lane>>4)*4+reg ; plane store
#pragma unroll
    for (int c = 0; c < 8; c++)
#pragma unroll
        for (int r = 0; r < 4; r++) {
            int grow = rowbase + wv * 16 + q * 4 + r;
            if (grow < N)
                Y[((size_t)(c >> 1) * N + grow) * 32 + (c & 1) * 16 + m] = (f16)acc[c][r];
        }
}

// ======== aggregation: 4 dim-planes, wave/node, 4 edges per iter ========
// layer0: h = f16( relu(nd*agg + b) * ns )   layer1: out = fp32(nd*agg + b)
__global__ __launch_bounds__(256) void aggF(
    const f16* __restrict__ YA, const int* __restrict__ rpA, const int* __restrict__ esA,
    const float* __restrict__ ndA, const float* __restrict__ nsA, const float* __restrict__ bA,
    float* __restrict__ oA, f16* __restrict__ hA, int nA4, int NA,
    const f16* __restrict__ YB, const int* __restrict__ rpB, const int* __restrict__ esB,
    const float* __restrict__ ndB, const float* __restrict__ nsB, const float* __restrict__ bB,
    float* __restrict__ oB, f16* __restrict__ hB, int nB4, int NB, int layer0) {
    const f16* Y; const int *rp, *es; const float *nd, *ns, *bias; float* out; f16* hout;
    int N, pass, blk;
    if ((int)blockIdx.x < 4 * nA4) {
        Y = YA; rp = rpA; es = esA; nd = ndA; ns = nsA; bias = bA; out = oA; hout = hA; N = NA;
        pass = blockIdx.x / nA4; blk = blockIdx.x % nA4;
    } else {
        int b2 = blockIdx.x - 4 * nA4;
        Y = YB; rp = rpB; es = esB; nd = ndB; ns = nsB; bias = bB; out = oB; hout = hB; N = NB;
        pass = b2 / nB4; blk = b2 % nB4;
    }
    int wave = threadIdx.x >> 6;
    int lane = threadIdx.x & 63;
    int node = blk * 4 + wave;
    if (node >= N) return;
    int sub = lane >> 4, d = lane & 15;
    int beg = rp[node], cnt = rp[node + 1] - beg;
    const f16x2* yp = (const f16x2*)(Y + (size_t)pass * N * 32);
    float ax = 0.f, ay = 0.f;
    for (int j = sub; j <= cnt; j += 4) {     // j==cnt -> virtual self-loop edge
        int s = (j < cnt) ? es[beg + j] : node;
        f16x2 v = yp[(size_t)s * 16 + d];
        ax += (float)v[0]; ay += (float)v[1];
    }
    ax += __shfl_xor(ax, 16); ay += __shfl_xor(ay, 16);
    ax += __shfl_xor(ax, 32); ay += __shfl_xor(ay, 32);
    if (lane < 16) {
        float ndv = nd[node];
        int dim = pass * 32 + 2 * d;
        float2 b = *(const float2*)(bias + dim);
        float ox = fmaf(ax, ndv, b.x);
        float oy = fmaf(ay, ndv, b.y);
        if (layer0) {
            ox = ox > 0.f ? ox : 0.f;
            oy = oy > 0.f ? oy : 0.f;
            float nsv = ns[node];
            f16x2 hv;
            hv[0] = (f16)(ox * nsv);
            hv[1] = (f16)(oy * nsv);
            *(f16x2*)(hout + (size_t)node * H + dim) = hv;
        } else {
            *(float2*)(out + (size_t)node * H + dim) = make_float2(ox, oy);
        }
    }
}

// ---------------- host ----------------

struct TypeBufs {
    int *rowptr, *esrc, *ch, *bb;
    u32 *binned, *part;
    float *norm_s, *norm_d;
    f16 *h, *y, *wt0, *wt1;
};

extern "C" void kernel_launch(void* const* d_in, const int* in_sizes, int n_in,
                              void* d_out, int out_size, void* d_ws, size_t ws_size,
                              hipStream_t stream) {
    (void)n_in; (void)out_size; (void)ws_size;
    const float* feat_a = (const float*)d_in[0];
    const float* feat_b = (const float*)d_in[1];
    const int* src_a = (const int*)d_in[2];
    const int* dst_a = (const int*)d_in[3];
    const int* src_b = (const int*)d_in[4];
    const int* dst_b = (const int*)d_in[5];
    const float* Wa0 = (const float*)d_in[6];
    const float* ba0 = (const float*)d_in[7];
    const float* Wa1 = (const float*)d_in[8];
    const float* ba1 = (const float*)d_in[9];
    const float* Wb0 = (const float*)d_in[10];
    const float* bb0 = (const float*)d_in[11];
    const float* Wb1 = (const float*)d_in[12];
    const float* bb1 = (const float*)d_in[13];

    const int DA = in_sizes[6] / H;   // 256
    const int DB = in_sizes[10] / H;  // 128
    const int NA = in_sizes[0] / DA;  // 50000
    const int NB = in_sizes[1] / DB;  // 30000
    const int EA = in_sizes[2];       // 600000
    const int EB = in_sizes[4];       // 300000

    const int nblkA = ceil_div(EA, EPB), nblkB = ceil_div(EB, EPB);
    const int nbinsA = ceil_div(NA, BUCK), nbinsB = ceil_div(NB, BUCK);
    const int LA = nbinsA * nblkA, LB = nbinsB * nblkB;
    const int nchA = ceil_div(NA, CHN), nchB = ceil_div(NB, CHN);

    char* w = (char*)d_ws;
    auto carve = [&](size_t bytes) {
        void* p = (void*)w;
        w += (bytes + 255) & ~(size_t)255;
        return p;
    };
    auto carve_type = [&](int N, int E, int D, int L, int nbins, int nch, int sl) {
        TypeBufs tb;
        tb.rowptr = (int*)carve(((size_t)N + 1) * 4);
        tb.esrc   = (int*)carve((size_t)E * 4);
        tb.ch     = (int*)carve((size_t)L * 4);
        tb.bb     = (int*)carve(((size_t)nbins + 1) * 4);
        tb.binned = (u32*)carve((size_t)E * 4);
        tb.part   = (u32*)carve((size_t)nch * sl * SLOTS * 4);
        tb.norm_s = (float*)carve((size_t)N * 4);
        tb.norm_d = (float*)carve((size_t)N * 4);
        tb.h      = (f16*)carve((size_t)N * H * 2);
        tb.y      = (f16*)carve((size_t)N * H * 2);
        tb.wt0    = (f16*)carve((size_t)D * H * 2);
        tb.wt1    = (f16*)carve((size_t)H * H * 2);
        return tb;
    };
    TypeBufs A = carve_type(NA, EA, DA, LA, nbinsA, nchA, SLA);
    TypeBufs B = carve_type(NB, EB, DB, LB, nbinsB, nchB, SLB);

    float* out_a = (float*)d_out;
    float* out_b = out_a + (size_t)NA * H;

    const int gblkA = ceil_div(NA, 64), gblkB = ceil_div(NB, 64);
    const int nA4 = ceil_div(NA, 4), nB4 = ceil_div(NB, 4);
    const int wcBlocks = (DA + 3 * H) / 2;
    const int histBlocks = nchA * SLA + nchB * SLB;

    // ---- prep (no device-scope atomics; 4 launches) ----
    prepK1<<<nblkA + nblkB + histBlocks + wcBlocks, 256, 0, stream>>>(
        dst_a, A.ch, EA, nblkA, nbinsA, dst_b, B.ch, EB, nblkB, nbinsB,
        src_a, A.part, NA, src_b, B.part, NB,
        Wa0, A.wt0, Wa1, A.wt1, Wb0, B.wt0, Wb1, B.wt1, DA);
    prepK2<<<2 + ceil_div(NA + NB, 256), 256, 0, stream>>>(
        A.ch, LA, A.bb, nbinsA, nblkA, EA, A.rowptr, NA,
        B.ch, LB, B.bb, nbinsB, nblkB, EB, B.rowptr, NB,
        A.part, A.norm_s, B.part, B.norm_s);
    p3K<<<nblkA + nblkB, 256, 0, stream>>>(src_a, dst_a, A.ch, A.binned, EA, nblkA, nbinsA,
                                           src_b, dst_b, B.ch, B.binned, EB, nblkB, nbinsB);
    p4K<<<nbinsA + nbinsB, 256, 0, stream>>>(A.binned, A.bb, nbinsA, A.rowptr, A.norm_d, A.esrc, NA,
                                             B.binned, B.bb, nbinsB, B.rowptr, B.norm_d, B.esrc, NB);
    // ---- layer 0 ----
    gemmF<<<gblkA + gblkB, 256, 0, stream>>>(
        feat_a, (const f16*)nullptr, A.wt0, A.norm_s, A.y, NA, DA, gblkA,
        feat_b, (const f16*)nullptr, B.wt0, B.norm_s, B.y, NB, DB, 0);
    aggF<<<4 * (nA4 + nB4), 256, 0, stream>>>(
        A.y, A.rowptr, A.esrc, A.norm_d, A.norm_s, ba0, out_a, A.h, nA4, NA,
        B.y, B.rowptr, B.esrc, B.norm_d, B.norm_s, bb0, out_b, B.h, nB4, NB, 1);
    // ---- layer 1 ----
    gemmF<<<gblkA + gblkB, 256, 0, stream>>>(
        (const float*)nullptr, A.h, A.wt1, A.norm_s, A.y, NA, H, gblkA,
        (const float*)nullptr, B.h, B.wt1, B.norm_s, B.y, NB, H, 1);
    aggF<<<4 * (nA4 + nB4), 256, 0, stream>>>(
        A.y, A.rowptr, A.esrc, A.norm_d, A.norm_s, ba1, out_a, A.h, nA4, NA,
        B.y, B.rowptr, B.esrc, B.norm_d, B.norm_s, bb1, out_b, B.h, nB4, NB, 0);
}

// Round 6
// 350.527 us; speedup vs baseline: 1.4677x; 1.4677x over previous
//
#include <hip/hip_runtime.h>
#include <hip/hip_bf16.h>

#define H 128
#define BK 64
#define LDSTR 72   // LDS row stride (f16 elems): 144B, 16B-aligned rows

#define EPB 4096        // edges per block, coarse passes
#define BUCK_BITS 8
#define BUCK 256        // nodes per bucket
#define CHN 25000       // nodes per deg-out chunk (16-bit packed counters, 50KB LDS)
#define SLOTS 12500
#define SLA 24          // edge slices per chunk, type A
#define SLB 16

typedef _Float16 f16;
typedef unsigned int u32;
typedef __attribute__((ext_vector_type(8))) _Float16 f16x8;
typedef __attribute__((ext_vector_type(4))) _Float16 f16x4;
typedef __attribute__((ext_vector_type(2))) _Float16 f16x2;
typedef __attribute__((ext_vector_type(4))) float floatx4;

static inline __host__ int ceil_div(int a, int b) { return (a + b - 1) / b; }

// ======== prep K1: coarse dst-hist | src-deg hist | weight transpose ========
__global__ __launch_bounds__(256) void prepK1(
    const int* __restrict__ dA, int* __restrict__ chA, int EA, int nblkA, int nbinsA,
    const int* __restrict__ dB, int* __restrict__ chB, int EB, int nblkB, int nbinsB,
    const int* __restrict__ sA, u32* __restrict__ pA, int NA,
    const int* __restrict__ sB, u32* __restrict__ pB, int NB,
    const float* __restrict__ Wa0, f16* ta0, const float* __restrict__ Wa1, f16* ta1,
    const float* __restrict__ Wb0, f16* tb0, const float* __restrict__ Wb1, f16* tb1, int DA) {
    __shared__ u32 shl[SLOTS];
    int bid = blockIdx.x;
    int t = threadIdx.x;
    int p1n = nblkA + nblkB;
    int nchA = (NA + CHN - 1) / CHN, nchB = (NB + CHN - 1) / CHN;
    int hn = nchA * SLA + nchB * SLB;
    if (bid < p1n) {
        int* bins = (int*)shl;
        const int* dst; int* ch; int E, nblk, nbins, blk;
        if (bid < nblkA) { dst = dA; ch = chA; E = EA; nblk = nblkA; nbins = nbinsA; blk = bid; }
        else { dst = dB; ch = chB; E = EB; nblk = nblkB; nbins = nbinsB; blk = bid - nblkA; }
        bins[t] = 0;
        __syncthreads();
        int e0 = blk * EPB, e1 = min(E, e0 + EPB);
        for (int e = e0 + t; e < e1; e += 256) atomicAdd(&bins[dst[e] >> BUCK_BITS], 1);
        __syncthreads();
        for (int b = t; b < nbins; b += 256) ch[b * nblk + blk] = bins[b];
    } else if (bid < p1n + hn) {
        int b2 = bid - p1n;
        const int* src; u32* part; int E, sl, chunk, g;
        if (b2 < nchA * SLA) { src = sA; part = pA; E = EA; sl = SLA; chunk = b2 / SLA; g = b2 % SLA; }
        else { b2 -= nchA * SLA; src = sB; part = pB; E = EB; sl = SLB; chunk = b2 / SLB; g = b2 % SLB; }
        for (int i = t; i < SLOTS; i += 256) shl[i] = 0;
        __syncthreads();
        int lo = chunk * CHN;
        int per = (E + sl - 1) / sl;
        int e0 = g * per, e1 = min(E, e0 + per);
        for (int e = e0 + t; e < e1; e += 256) {
            int s = src[e] - lo;
            if ((unsigned)s < (unsigned)CHN) atomicAdd(&shl[s >> 1], 1u << ((s & 1) << 4));
        }
        __syncthreads();
        u32* dp = part + (size_t)(chunk * sl + g) * SLOTS;
        for (int i = t; i < SLOTS; i += 256) dp[i] = shl[i];
    } else {
        int b2 = bid - p1n - hn;           // weight transpose: 2 k-rows per block
        int k2 = b2 * 2 + (t >> 7);
        const float* W; f16* T; int D, k;
        if (k2 < DA) { W = Wa0; T = ta0; D = DA; k = k2; }
        else if (k2 < DA + H) { W = Wa1; T = ta1; D = H; k = k2 - DA; }
        else if (k2 < DA + 2 * H) { W = Wb0; T = tb0; D = H; k = k2 - DA - H; }
        else { W = Wb1; T = tb1; D = H; k = k2 - DA - 2 * H; }
        int c = t & 127;
        T[(size_t)c * D + k] = (f16)W[(size_t)k * H + c];
    }
}

// ======== prep K2: scan of (bucket x block) matrix | deg-out reduce ========
__global__ __launch_bounds__(256) void prepK2(
    int* chA, int LA, int* bbA, int nbinsA, int nblkA, int EA, int* rpA, int NA,
    int* chB, int LB, int* bbB, int nbinsB, int nblkB, int EB, int* rpB, int NB,
    const u32* __restrict__ pA, float* __restrict__ nsA,
    const u32* __restrict__ pB, float* __restrict__ nsB) {
    __shared__ int sh[256];
    int bid = blockIdx.x, t = threadIdx.x;
    if (bid < 2) {
        int* ch; int L; int* bb; int nbins, nblk, E; int* rp; int N;
        if (bid == 0) { ch = chA; L = LA; bb = bbA; nbins = nbinsA; nblk = nblkA; E = EA; rp = rpA; N = NA; }
        else { ch = chB; L = LB; bb = bbB; nbins = nbinsB; nblk = nblkB; E = EB; rp = rpB; N = NB; }
        int per = (L + 255) >> 8;
        int lo = t * per, hi = min(lo + per, L);
        int s = 0;
        for (int i = lo; i < hi; i++) s += ch[i];
        sh[t] = s;
        __syncthreads();
        for (int off = 1; off < 256; off <<= 1) {
            int x = (t >= off) ? sh[t - off] : 0;
            __syncthreads();
            sh[t] += x;
            __syncthreads();
        }
        int run = sh[t] - s;
        for (int i = lo; i < hi; i++) { int v = ch[i]; ch[i] = run; run += v; }
        __syncthreads();
        for (int b = t; b <= nbins; b += 256) bb[b] = (b < nbins) ? ch[b * nblk] : E;
        if (t == 0) rp[N] = E;
    } else {
        int i = (bid - 2) * 256 + t;
        const u32* part; float* ns; int sl, idx;
        if (i < NA) { part = pA; ns = nsA; sl = SLA; idx = i; }
        else if (i < NA + NB) { part = pB; ns = nsB; sl = SLB; idx = i - NA; }
        else return;
        int chunk = idx / CHN, local = idx % CHN;
        int slot = local >> 1, shf = (local & 1) << 4;
        u32 sum = 0;
        const u32* base = part + (size_t)chunk * sl * SLOTS + slot;
        for (int g = 0; g < sl; g++) sum += base[(size_t)g * SLOTS];
        int deg = (int)((sum >> shf) & 0xFFFFu);
        ns[idx] = rsqrtf((float)(deg + 1));
    }
}

// ======== P3: scatter edges to bucket-ordered array (plain stores) ========
__global__ __launch_bounds__(256) void p3K(
    const int* __restrict__ sA, const int* __restrict__ dA, const int* __restrict__ chA,
    u32* __restrict__ binA, int EA, int nblkA, int nbinsA,
    const int* __restrict__ sB, const int* __restrict__ dB, const int* __restrict__ chB,
    u32* __restrict__ binB, int EB, int nblkB, int nbinsB) {
    __shared__ int bins[BUCK];
    __shared__ int off[BUCK];
    const int *src, *dst; const int* ch; u32* bin; int E, nblk, nbins, blk;
    if ((int)blockIdx.x < nblkA) {
        src = sA; dst = dA; ch = chA; bin = binA; E = EA; nblk = nblkA; nbins = nbinsA; blk = blockIdx.x;
    } else {
        src = sB; dst = dB; ch = chB; bin = binB; E = EB; nblk = nblkB; nbins = nbinsB; blk = blockIdx.x - nblkA;
    }
    int t = threadIdx.x;
    bins[t] = 0;
    if (t < nbins) off[t] = ch[t * nblk + blk];
    __syncthreads();
    int e0 = blk * EPB, e1 = min(E, e0 + EPB);
    for (int e = e0 + t; e < e1; e += 256) {
        int d = dst[e], s = src[e];
        int b = d >> BUCK_BITS;
        int r = atomicAdd(&bins[b], 1);
        bin[off[b] + r] = (u32)s | ((u32)(d & (BUCK - 1)) << 16);
    }
}

// ======== P4: per-bucket fine pass -> norm_d, rowptr, esrc ========
__global__ __launch_bounds__(256) void p4K(
    const u32* __restrict__ binA, const int* __restrict__ bbA, int nbinsA,
    int* __restrict__ rpA, float* __restrict__ ndA, int* __restrict__ esA, int NA,
    const u32* __restrict__ binB, const int* __restrict__ bbB, int nbinsB,
    int* __restrict__ rpB, float* __restrict__ ndB, int* __restrict__ esB, int NB) {
    __shared__ int cnt[BUCK], pos[BUCK], fill[BUCK];
    const u32* bin; const int* bb; int* rp; float* nd; int* es; int N, blk;
    if ((int)blockIdx.x < nbinsA) {
        bin = binA; bb = bbA; rp = rpA; nd = ndA; es = esA; N = NA; blk = blockIdx.x;
    } else {
        bin = binB; bb = bbB; rp = rpB; nd = ndB; es = esB; N = NB; blk = blockIdx.x - nbinsA;
    }
    int t = threadIdx.x;
    int e0 = bb[blk], e1 = bb[blk + 1];
    cnt[t] = 0; fill[t] = 0;
    __syncthreads();
    for (int e = e0 + t; e < e1; e += 256) atomicAdd(&cnt[(bin[e] >> 16) & 255], 1);
    __syncthreads();
    int c = cnt[t];
    int node = (blk << BUCK_BITS) + t;
    if (node < N) nd[node] = rsqrtf((float)(c + 1));
    pos[t] = c;
    __syncthreads();
    for (int off = 1; off < 256; off <<= 1) {
        int x = (t >= off) ? pos[t - off] : 0;
        __syncthreads();
        pos[t] += x;
        __syncthreads();
    }
    int start = e0 + pos[t] - c;
    pos[t] = start;
    if (node < N) rp[node] = start;
    __syncthreads();
    for (int e = e0 + t; e < e1; e += 256) {
        u32 w = bin[e];
        int i = (w >> 16) & 255;
        int r = atomicAdd(&fill[i], 1);
        es[pos[i] + r] = (int)(w & 0xFFFFu);
    }
}

// ======== MFMA GEMM (f16, merged A+B): Y = f16( (X*ns) @ W ), contiguous rows ========
__global__ __launch_bounds__(256) void gemmF(
    const float* __restrict__ X32A, const f16* __restrict__ X16A, const f16* __restrict__ WtA,
    const float* __restrict__ nsA, f16* __restrict__ YA, int NA, int DA, int nblkA,
    const float* __restrict__ X32B, const f16* __restrict__ X16B, const f16* __restrict__ WtB,
    const float* __restrict__ nsB, f16* __restrict__ YB, int NB, int DB, int xf16) {
    const float* X32; const f16* X16; const f16* Wt; const float* ns; f16* Y; int N, D, bid;
    if ((int)blockIdx.x < nblkA) {
        X32 = X32A; X16 = X16A; Wt = WtA; ns = nsA; Y = YA; N = NA; D = DA; bid = blockIdx.x;
    } else {
        X32 = X32B; X16 = X16B; Wt = WtB; ns = nsB; Y = YB; N = NB; D = DB; bid = blockIdx.x - nblkA;
    }
    __shared__ f16 Xs[64 * LDSTR];
    __shared__ f16 Ws[128 * LDSTR];
    int t = threadIdx.x;
    int wv = t >> 6, lane = t & 63;
    int m = lane & 15, q = lane >> 4;
    int rowbase = bid * 64;

    floatx4 acc[8];
#pragma unroll
    for (int c = 0; c < 8; c++) acc[c] = (floatx4)(0.f);

    for (int k0 = 0; k0 < D; k0 += BK) {
        __syncthreads();
        if (xf16) {   // stage pre-scaled f16 X: plain 16B copies
            int kq = (t & 7) * 8;
            int r0 = t >> 3;
#pragma unroll
            for (int i = 0; i < 2; i++) {
                int r = r0 + i * 32;
                int grow = rowbase + r;
                f16x8 v = (f16x8)(f16)0;
                if (grow < N) v = *(const f16x8*)(X16 + (size_t)grow * D + k0 + kq);
                *(f16x8*)&Xs[r * LDSTR + kq] = v;
            }
        } else {      // stage fp32 X: fold norm_s, convert to f16
            int kq = (t & 15) * 4;
#pragma unroll
            for (int i = 0; i < 4; i++) {
                int r = (t >> 4) + i * 16;
                int grow = rowbase + r;
                float4 v = make_float4(0.f, 0.f, 0.f, 0.f);
                float nv = 0.f;
                if (grow < N) {
                    v = *(const float4*)(X32 + (size_t)grow * D + k0 + kq);
                    nv = ns[grow];
                }
                f16x4 hv;
                hv[0] = (f16)(v.x * nv); hv[1] = (f16)(v.y * nv);
                hv[2] = (f16)(v.z * nv); hv[3] = (f16)(v.w * nv);
                *(f16x4*)&Xs[r * LDSTR + kq] = hv;
            }
        }
        {   // stage W chunk: 128 c x 64 k
            int ks = (t & 7) * 8;
            int rb = t >> 3;
#pragma unroll
            for (int i = 0; i < 4; i++) {
                int c = rb + i * 32;
                *(f16x8*)&Ws[c * LDSTR + ks] = *(const f16x8*)&Wt[(size_t)c * D + k0 + ks];
            }
        }
        __syncthreads();
#pragma unroll
        for (int ks = 0; ks < BK; ks += 32) {
            f16x8 a = *(const f16x8*)&Xs[(wv * 16 + m) * LDSTR + ks + q * 8];
#pragma unroll
            for (int c = 0; c < 8; c++) {
                f16x8 b = *(const f16x8*)&Ws[(c * 16 + m) * LDSTR + ks + q * 8];
                acc[c] = __builtin_amdgcn_mfma_f32_16x16x32_f16(a, b, acc[c], 0, 0, 0);
            }
        }
    }
    // D layout col=lane&15, row=(lane>>4)*4+reg ; contiguous f16 row store
#pragma unroll
    for (int c = 0; c < 8; c++)
#pragma unroll
        for (int r = 0; r < 4; r++) {
            int grow = rowbase + wv * 16 + q * 4 + r;
            if (grow < N) Y[(size_t)grow * H + c * 16 + m] = (f16)acc[c][r];
        }
}

// ======== aggregation: 1 wave/node, 16 lanes x f16x8 per edge, 8 edges in flight ========
// layer0: h = f16( relu(nd*agg + b) * ns )   layer1: out = fp32(nd*agg + b)
__global__ __launch_bounds__(256) void aggC(
    const f16* __restrict__ YA, const int* __restrict__ rpA, const int* __restrict__ esA,
    const float* __restrict__ ndA, const float* __restrict__ nsA, const float* __restrict__ bA,
    float* __restrict__ oA, f16* __restrict__ hA, int nA4, int NA,
    const f16* __restrict__ YB, const int* __restrict__ rpB, const int* __restrict__ esB,
    const float* __restrict__ ndB, const float* __restrict__ nsB, const float* __restrict__ bB,
    float* __restrict__ oB, f16* __restrict__ hB, int NB, int layer0) {
    const f16* Y; const int *rp, *es; const float *nd, *ns, *bias; float* out; f16* hout;
    int N, blk;
    if ((int)blockIdx.x < nA4) {
        Y = YA; rp = rpA; es = esA; nd = ndA; ns = nsA; bias = bA; out = oA; hout = hA;
        N = NA; blk = blockIdx.x;
    } else {
        Y = YB; rp = rpB; es = esB; nd = ndB; ns = nsB; bias = bB; out = oB; hout = hB;
        N = NB; blk = blockIdx.x - nA4;
    }
    int wave = threadIdx.x >> 6;
    int lane = threadIdx.x & 63;
    int node = blk * 4 + wave;
    if (node >= N) return;
    int sub = lane >> 4, d = lane & 15;    // sub 0..3 handles edges j%4==sub; d: 8-dim group
    int beg = rp[node], cnt = rp[node + 1] - beg;
    int tot = cnt + 1;                     // +1 virtual self-loop edge (index cnt -> node)
    float acc[8];
#pragma unroll
    for (int i = 0; i < 8; i++) acc[i] = 0.f;
    int j = sub;
    for (; j + 4 < tot; j += 8) {          // two edges per iteration per sub
        int s0 = (j < cnt) ? es[beg + j] : node;
        int s1 = (j + 4 < cnt) ? es[beg + j + 4] : node;
        f16x8 v0 = *(const f16x8*)(Y + (size_t)s0 * H + d * 8);
        f16x8 v1 = *(const f16x8*)(Y + (size_t)s1 * H + d * 8);
#pragma unroll
        for (int i = 0; i < 8; i++) acc[i] += (float)v0[i] + (float)v1[i];
    }
    if (j < tot) {
        int s0 = (j < cnt) ? es[beg + j] : node;
        f16x8 v0 = *(const f16x8*)(Y + (size_t)s0 * H + d * 8);
#pragma unroll
        for (int i = 0; i < 8; i++) acc[i] += (float)v0[i];
    }
    // reduce across the 4 subs (lane bits 4,5)
#pragma unroll
    for (int i = 0; i < 8; i++) {
        acc[i] += __shfl_xor(acc[i], 16);
        acc[i] += __shfl_xor(acc[i], 32);
    }
    if (lane < 16) {
        float ndv = nd[node];
        float4 b0 = *(const float4*)(bias + d * 8);
        float4 b1 = *(const float4*)(bias + d * 8 + 4);
        float o0 = fmaf(acc[0], ndv, b0.x), o1 = fmaf(acc[1], ndv, b0.y);
        float o2 = fmaf(acc[2], ndv, b0.z), o3 = fmaf(acc[3], ndv, b0.w);
        float o4 = fmaf(acc[4], ndv, b1.x), o5 = fmaf(acc[5], ndv, b1.y);
        float o6 = fmaf(acc[6], ndv, b1.z), o7 = fmaf(acc[7], ndv, b1.w);
        if (layer0) {
            float nsv = ns[node];
            f16x8 hv;
            hv[0] = (f16)(fmaxf(o0, 0.f) * nsv); hv[1] = (f16)(fmaxf(o1, 0.f) * nsv);
            hv[2] = (f16)(fmaxf(o2, 0.f) * nsv); hv[3] = (f16)(fmaxf(o3, 0.f) * nsv);
            hv[4] = (f16)(fmaxf(o4, 0.f) * nsv); hv[5] = (f16)(fmaxf(o5, 0.f) * nsv);
            hv[6] = (f16)(fmaxf(o6, 0.f) * nsv); hv[7] = (f16)(fmaxf(o7, 0.f) * nsv);
            *(f16x8*)(hout + (size_t)node * H + d * 8) = hv;
        } else {
            float* op = out + (size_t)node * H + d * 8;
            *(float4*)op = make_float4(o0, o1, o2, o3);
            *(float4*)(op + 4) = make_float4(o4, o5, o6, o7);
        }
    }
}

// ---------------- host ----------------

struct TypeBufs {
    int *rowptr, *esrc, *ch, *bb;
    u32 *binned, *part;
    float *norm_s, *norm_d;
    f16 *h, *y, *wt0, *wt1;
};

extern "C" void kernel_launch(void* const* d_in, const int* in_sizes, int n_in,
                              void* d_out, int out_size, void* d_ws, size_t ws_size,
                              hipStream_t stream) {
    (void)n_in; (void)out_size; (void)ws_size;
    const float* feat_a = (const float*)d_in[0];
    const float* feat_b = (const float*)d_in[1];
    const int* src_a = (const int*)d_in[2];
    const int* dst_a = (const int*)d_in[3];
    const int* src_b = (const int*)d_in[4];
    const int* dst_b = (const int*)d_in[5];
    const float* Wa0 = (const float*)d_in[6];
    const float* ba0 = (const float*)d_in[7];
    const float* Wa1 = (const float*)d_in[8];
    const float* ba1 = (const float*)d_in[9];
    const float* Wb0 = (const float*)d_in[10];
    const float* bb0 = (const float*)d_in[11];
    const float* Wb1 = (const float*)d_in[12];
    const float* bb1 = (const float*)d_in[13];

    const int DA = in_sizes[6] / H;   // 256
    const int DB = in_sizes[10] / H;  // 128
    const int NA = in_sizes[0] / DA;  // 50000
    const int NB = in_sizes[1] / DB;  // 30000
    const int EA = in_sizes[2];       // 600000
    const int EB = in_sizes[4];       // 300000

    const int nblkA = ceil_div(EA, EPB), nblkB = ceil_div(EB, EPB);
    const int nbinsA = ceil_div(NA, BUCK), nbinsB = ceil_div(NB, BUCK);
    const int LA = nbinsA * nblkA, LB = nbinsB * nblkB;
    const int nchA = ceil_div(NA, CHN), nchB = ceil_div(NB, CHN);

    char* w = (char*)d_ws;
    auto carve = [&](size_t bytes) {
        void* p = (void*)w;
        w += (bytes + 255) & ~(size_t)255;
        return p;
    };
    auto carve_type = [&](int N, int E, int D, int L, int nbins, int nch, int sl) {
        TypeBufs tb;
        tb.rowptr = (int*)carve(((size_t)N + 1) * 4);
        tb.esrc   = (int*)carve((size_t)E * 4);
        tb.ch     = (int*)carve((size_t)L * 4);
        tb.bb     = (int*)carve(((size_t)nbins + 1) * 4);
        tb.binned = (u32*)carve((size_t)E * 4);
        tb.part   = (u32*)carve((size_t)nch * sl * SLOTS * 4);
        tb.norm_s = (float*)carve((size_t)N * 4);
        tb.norm_d = (float*)carve((size_t)N * 4);
        tb.h      = (f16*)carve((size_t)N * H * 2);
        tb.y      = (f16*)carve((size_t)N * H * 2);
        tb.wt0    = (f16*)carve((size_t)D * H * 2);
        tb.wt1    = (f16*)carve((size_t)H * H * 2);
        return tb;
    };
    TypeBufs A = carve_type(NA, EA, DA, LA, nbinsA, nchA, SLA);
    TypeBufs B = carve_type(NB, EB, DB, LB, nbinsB, nchB, SLB);

    float* out_a = (float*)d_out;
    float* out_b = out_a + (size_t)NA * H;

    const int gblkA = ceil_div(NA, 64), gblkB = ceil_div(NB, 64);
    const int nA4 = ceil_div(NA, 4), nB4 = ceil_div(NB, 4);
    const int wcBlocks = (DA + 3 * H) / 2;
    const int histBlocks = nchA * SLA + nchB * SLB;

    // ---- prep (no device-scope atomics; 4 launches) ----
    prepK1<<<nblkA + nblkB + histBlocks + wcBlocks, 256, 0, stream>>>(
        dst_a, A.ch, EA, nblkA, nbinsA, dst_b, B.ch, EB, nblkB, nbinsB,
        src_a, A.part, NA, src_b, B.part, NB,
        Wa0, A.wt0, Wa1, A.wt1, Wb0, B.wt0, Wb1, B.wt1, DA);
    prepK2<<<2 + ceil_div(NA + NB, 256), 256, 0, stream>>>(
        A.ch, LA, A.bb, nbinsA, nblkA, EA, A.rowptr, NA,
        B.ch, LB, B.bb, nbinsB, nblkB, EB, B.rowptr, NB,
        A.part, A.norm_s, B.part, B.norm_s);
    p3K<<<nblkA + nblkB, 256, 0, stream>>>(src_a, dst_a, A.ch, A.binned, EA, nblkA, nbinsA,
                                           src_b, dst_b, B.ch, B.binned, EB, nblkB, nbinsB);
    p4K<<<nbinsA + nbinsB, 256, 0, stream>>>(A.binned, A.bb, nbinsA, A.rowptr, A.norm_d, A.esrc, NA,
                                             B.binned, B.bb, nbinsB, B.rowptr, B.norm_d, B.esrc, NB);
    // ---- layer 0 ----
    gemmF<<<gblkA + gblkB, 256, 0, stream>>>(
        feat_a, (const f16*)nullptr, A.wt0, A.norm_s, A.y, NA, DA, gblkA,
        feat_b, (const f16*)nullptr, B.wt0, B.norm_s, B.y, NB, DB, 0);
    aggC<<<nA4 + nB4, 256, 0, stream>>>(
        A.y, A.rowptr, A.esrc, A.norm_d, A.norm_s, ba0, out_a, A.h, nA4, NA,
        B.y, B.rowptr, B.esrc, B.norm_d, B.norm_s, bb0, out_b, B.h, NB, 1);
    // ---- layer 1 ----
    gemmF<<<gblkA + gblkB, 256, 0, stream>>>(
        (const float*)nullptr, A.h, A.wt1, A.norm_s, A.y, NA, H, gblkA,
        (const float*)nullptr, B.h, B.wt1, B.norm_s, B.y, NB, H, 1);
    aggC<<<nA4 + nB4, 256, 0, stream>>>(
        A.y, A.rowptr, A.esrc, A.norm_d, A.norm_s, ba1, out_a, A.h, nA4, NA,
        B.y, B.rowptr, B.esrc, B.norm_d, B.norm_s, bb1, out_b, B.h, NB, 0);
}

// Round 7
// 283.743 us; speedup vs baseline: 1.8131x; 1.2354x over previous
//
#include <hip/hip_runtime.h>
#include <hip/hip_bf16.h>

#define H 128
#define BK 64
#define LDSTR 72   // LDS row stride (f16 elems): 144B, 16B-aligned rows

#define EPB 4096        // edges per block, bucket passes
#define BUCK_BITS 8
#define BUCK 256        // nodes per bucket

typedef _Float16 f16;
typedef unsigned int u32;
typedef __attribute__((ext_vector_type(8))) _Float16 f16x8;
typedef __attribute__((ext_vector_type(4))) _Float16 f16x4;
typedef __attribute__((ext_vector_type(4))) float floatx4;

static inline __host__ int ceil_div(int a, int b) { return (a + b - 1) / b; }

// ======== P1: per-block 256-bin histograms of dst>>8 AND src>>8 | weight transpose ========
__global__ __launch_bounds__(256) void p1K(
    const int* __restrict__ sA, const int* __restrict__ dA, int EA, int nblkA, int nbinsA,
    const int* __restrict__ sB, const int* __restrict__ dB, int EB, int nblkB, int nbinsB,
    int* __restrict__ ch, int offAd, int offBd, int offAs, int offBs, int Lall,
    const float* __restrict__ Wa0, f16* ta0, const float* __restrict__ Wa1, f16* ta1,
    const float* __restrict__ Wb0, f16* tb0, const float* __restrict__ Wb1, f16* tb1, int DA) {
    __shared__ int bd[BUCK], bs[BUCK];
    int bid = blockIdx.x, t = threadIdx.x;
    int p1n = nblkA + nblkB;
    if (bid < p1n) {
        const int *src, *dst; int E, nblk, nbins, blk, od, os;
        if (bid < nblkA) { src = sA; dst = dA; E = EA; nblk = nblkA; nbins = nbinsA; blk = bid; od = offAd; os = offAs; }
        else { src = sB; dst = dB; E = EB; nblk = nblkB; nbins = nbinsB; blk = bid - nblkA; od = offBd; os = offBs; }
        bd[t] = 0; bs[t] = 0;
        __syncthreads();
        int e0 = blk * EPB, e1 = min(E, e0 + EPB);
        for (int e = e0 + t; e < e1; e += 256) {
            atomicAdd(&bd[dst[e] >> BUCK_BITS], 1);
            atomicAdd(&bs[src[e] >> BUCK_BITS], 1);
        }
        __syncthreads();
        for (int b = t; b < nbins; b += 256) {
            ch[od + b * nblk + blk] = bd[b];
            ch[os + b * nblk + blk] = bs[b];
        }
        if (bid == 0 && t == 0) ch[Lall] = 0;   // sentinel -> scanned value = grand total
    } else {
        int b2 = bid - p1n;                      // weight transpose: 2 k-rows per block
        int k2 = b2 * 2 + (t >> 7);
        const float* W; f16* T; int D, k;
        if (k2 < DA) { W = Wa0; T = ta0; D = DA; k = k2; }
        else if (k2 < DA + H) { W = Wa1; T = ta1; D = H; k = k2 - DA; }
        else if (k2 < DA + 2 * H) { W = Wb0; T = tb0; D = H; k = k2 - DA - H; }
        else { W = Wb1; T = tb1; D = H; k = k2 - DA - 2 * H; }
        int c = t & 127;
        T[(size_t)c * D + k] = (f16)W[(size_t)k * H + c];
    }
}

// ======== generic 3-phase exclusive scan over ch[0..n) (in-place) ========
__global__ __launch_bounds__(256) void scan1K(int* __restrict__ ch, int n, int* __restrict__ bsum) {
    __shared__ int sh[256];
    int t = threadIdx.x;
    int base = blockIdx.x * 1024 + t * 4;
    int v[4];
#pragma unroll
    for (int i = 0; i < 4; i++) v[i] = (base + i < n) ? ch[base + i] : 0;
    int s = v[0] + v[1] + v[2] + v[3];
    sh[t] = s;
    __syncthreads();
    for (int off = 1; off < 256; off <<= 1) {
        int x = (t >= off) ? sh[t - off] : 0;
        __syncthreads();
        sh[t] += x;
        __syncthreads();
    }
    int run = sh[t] - s;
#pragma unroll
    for (int i = 0; i < 4; i++) {
        if (base + i < n) ch[base + i] = run;
        run += v[i];
    }
    if (t == 255) bsum[blockIdx.x] = sh[255];
}

__global__ void scan2K(int* bsum, int nb) {      // up to 256 block sums
    __shared__ int sh[256];
    int t = threadIdx.x;
    int v = (t < nb) ? bsum[t] : 0;
    sh[t] = v;
    __syncthreads();
    for (int off = 1; off < 256; off <<= 1) {
        int x = (t >= off) ? sh[t - off] : 0;
        __syncthreads();
        sh[t] += x;
        __syncthreads();
    }
    if (t < nb) bsum[t] = sh[t] - v;
}

__global__ void scan3K(int* __restrict__ ch, const int* __restrict__ bsum, int n) {
    int i = blockIdx.x * 256 + threadIdx.x;
    if (i < n) ch[i] += bsum[i >> 10];
}

// ======== P3: scatter edges into bucket-ordered array, dst-keyed AND src-keyed ========
__global__ __launch_bounds__(256) void p3K(
    const int* __restrict__ sA, const int* __restrict__ dA, int EA, int nblkA, int nbinsA,
    const int* __restrict__ sB, const int* __restrict__ dB, int EB, int nblkB, int nbinsB,
    const int* __restrict__ ch, int offAd, int offBd, int offAs, int offBs,
    u32* __restrict__ binned) {
    __shared__ int cd[BUCK], cs[BUCK], ofd[BUCK], ofs[BUCK];
    const int *src, *dst; int E, nblk, nbins, blk, od, os;
    if ((int)blockIdx.x < nblkA) {
        src = sA; dst = dA; E = EA; nblk = nblkA; nbins = nbinsA; blk = blockIdx.x; od = offAd; os = offAs;
    } else {
        src = sB; dst = dB; E = EB; nblk = nblkB; nbins = nbinsB; blk = blockIdx.x - nblkA; od = offBd; os = offBs;
    }
    int t = threadIdx.x;
    cd[t] = 0; cs[t] = 0;
    if (t < nbins) {
        ofd[t] = ch[od + t * nblk + blk];
        ofs[t] = ch[os + t * nblk + blk];
    }
    __syncthreads();
    int e0 = blk * EPB, e1 = min(E, e0 + EPB);
    for (int e = e0 + t; e < e1; e += 256) {
        int d = dst[e], s = src[e];
        int b = d >> BUCK_BITS;
        int r = atomicAdd(&cd[b], 1);
        binned[ofd[b] + r] = (u32)s | ((u32)(d & (BUCK - 1)) << 16);
        int b2 = s >> BUCK_BITS;
        int r2 = atomicAdd(&cs[b2], 1);
        binned[ofs[b2] + r2] = (u32)(s & (BUCK - 1));
    }
}

// ======== P4: per-bucket fine pass. dst-buckets: norm_d+rowptr+esrc; src-buckets: norm_s ========
__global__ __launch_bounds__(256) void p4K(
    const u32* __restrict__ binned, const int* __restrict__ ch,
    int nbinsA, int nblkA, int offAd, int offAs,
    int nbinsB, int nblkB, int offBd, int offBs,
    int* __restrict__ rpA, float* __restrict__ ndA, int* __restrict__ esA, int NA, int EA,
    int* __restrict__ rpB, float* __restrict__ ndB, int* __restrict__ esB, int NB, int EB,
    float* __restrict__ nsA, float* __restrict__ nsB) {
    __shared__ int cnt[BUCK], pos[BUCK], fill[BUCK];
    int bid = blockIdx.x, t = threadIdx.x;
    int ndst = nbinsA + nbinsB;
    if (bid == 0 && t == 0) { rpA[NA] = EA; rpB[NB] = EB; }
    if (bid < ndst) {
        // ---- dst bucket: full CSR ----
        int blk, offm, nblkm, N, ebase; int* rp; float* nd; int* es;
        if (bid < nbinsA) { blk = bid; offm = offAd; nblkm = nblkA; rp = rpA; nd = ndA; es = esA; N = NA; ebase = 0; }
        else { blk = bid - nbinsA; offm = offBd; nblkm = nblkB; rp = rpB; nd = ndB; es = esB; N = NB; ebase = EA; }
        int e0 = ch[offm + blk * nblkm];
        int e1 = ch[offm + (blk + 1) * nblkm];   // next bucket start (or next matrix start)
        cnt[t] = 0; fill[t] = 0;
        __syncthreads();
        for (int e = e0 + t; e < e1; e += 256) atomicAdd(&cnt[(binned[e] >> 16) & 255], 1);
        __syncthreads();
        int c = cnt[t];
        int node = (blk << BUCK_BITS) + t;
        if (node < N) nd[node] = rsqrtf((float)(c + 1));
        pos[t] = c;
        __syncthreads();
        for (int off = 1; off < 256; off <<= 1) {
            int x = (t >= off) ? pos[t - off] : 0;
            __syncthreads();
            pos[t] += x;
            __syncthreads();
        }
        int start = e0 + pos[t] - c - ebase;     // within-type CSR start
        pos[t] = start;
        if (node < N) rp[node] = start;
        __syncthreads();
        for (int e = e0 + t; e < e1; e += 256) {
            u32 w = binned[e];
            int i = (w >> 16) & 255;
            int r = atomicAdd(&fill[i], 1);
            es[pos[i] + r] = (int)(w & 0xFFFFu);
        }
    } else {
        // ---- src bucket: count only -> norm_s ----
        int b2 = bid - ndst;
        int blk, offm, nblkm, N; float* ns;
        if (b2 < nbinsA) { blk = b2; offm = offAs; nblkm = nblkA; ns = nsA; N = NA; }
        else { blk = b2 - nbinsA; offm = offBs; nblkm = nblkB; ns = nsB; N = NB; }
        int e0 = ch[offm + blk * nblkm];
        int e1 = ch[offm + (blk + 1) * nblkm];
        cnt[t] = 0;
        __syncthreads();
        for (int e = e0 + t; e < e1; e += 256) atomicAdd(&cnt[binned[e] & 255], 1);
        __syncthreads();
        int node = (blk << BUCK_BITS) + t;
        if (node < N) ns[node] = rsqrtf((float)(cnt[t] + 1));
    }
}

// ======== MFMA GEMM (f16, merged A+B): Y = f16( (X*ns) @ W ), contiguous rows ========
__global__ __launch_bounds__(256) void gemmF(
    const float* __restrict__ X32A, const f16* __restrict__ X16A, const f16* __restrict__ WtA,
    const float* __restrict__ nsA, f16* __restrict__ YA, int NA, int DA, int nblkA,
    const float* __restrict__ X32B, const f16* __restrict__ X16B, const f16* __restrict__ WtB,
    const float* __restrict__ nsB, f16* __restrict__ YB, int NB, int DB, int xf16) {
    const float* X32; const f16* X16; const f16* Wt; const float* ns; f16* Y; int N, D, bid;
    if ((int)blockIdx.x < nblkA) {
        X32 = X32A; X16 = X16A; Wt = WtA; ns = nsA; Y = YA; N = NA; D = DA; bid = blockIdx.x;
    } else {
        X32 = X32B; X16 = X16B; Wt = WtB; ns = nsB; Y = YB; N = NB; D = DB; bid = blockIdx.x - nblkA;
    }
    __shared__ f16 Xs[64 * LDSTR];
    __shared__ f16 Ws[128 * LDSTR];
    int t = threadIdx.x;
    int wv = t >> 6, lane = t & 63;
    int m = lane & 15, q = lane >> 4;
    int rowbase = bid * 64;

    floatx4 acc[8];
#pragma unroll
    for (int c = 0; c < 8; c++) acc[c] = (floatx4)(0.f);

    for (int k0 = 0; k0 < D; k0 += BK) {
        __syncthreads();
        if (xf16) {   // stage pre-scaled f16 X: plain 16B copies
            int kq = (t & 7) * 8;
            int r0 = t >> 3;
#pragma unroll
            for (int i = 0; i < 2; i++) {
                int r = r0 + i * 32;
                int grow = rowbase + r;
                f16x8 v = (f16x8)(f16)0;
                if (grow < N) v = *(const f16x8*)(X16 + (size_t)grow * D + k0 + kq);
                *(f16x8*)&Xs[r * LDSTR + kq] = v;
            }
        } else {      // stage fp32 X: fold norm_s, convert to f16
            int kq = (t & 15) * 4;
#pragma unroll
            for (int i = 0; i < 4; i++) {
                int r = (t >> 4) + i * 16;
                int grow = rowbase + r;
                float4 v = make_float4(0.f, 0.f, 0.f, 0.f);
                float nv = 0.f;
                if (grow < N) {
                    v = *(const float4*)(X32 + (size_t)grow * D + k0 + kq);
                    nv = ns[grow];
                }
                f16x4 hv;
                hv[0] = (f16)(v.x * nv); hv[1] = (f16)(v.y * nv);
                hv[2] = (f16)(v.z * nv); hv[3] = (f16)(v.w * nv);
                *(f16x4*)&Xs[r * LDSTR + kq] = hv;
            }
        }
        {   // stage W chunk: 128 c x 64 k
            int ks = (t & 7) * 8;
            int rb = t >> 3;
#pragma unroll
            for (int i = 0; i < 4; i++) {
                int c = rb + i * 32;
                *(f16x8*)&Ws[c * LDSTR + ks] = *(const f16x8*)&Wt[(size_t)c * D + k0 + ks];
            }
        }
        __syncthreads();
#pragma unroll
        for (int ks = 0; ks < BK; ks += 32) {
            f16x8 a = *(const f16x8*)&Xs[(wv * 16 + m) * LDSTR + ks + q * 8];
#pragma unroll
            for (int c = 0; c < 8; c++) {
                f16x8 b = *(const f16x8*)&Ws[(c * 16 + m) * LDSTR + ks + q * 8];
                acc[c] = __builtin_amdgcn_mfma_f32_16x16x32_f16(a, b, acc[c], 0, 0, 0);
            }
        }
    }
    // D layout col=lane&15, row=(lane>>4)*4+reg ; contiguous f16 row store
#pragma unroll
    for (int c = 0; c < 8; c++)
#pragma unroll
        for (int r = 0; r < 4; r++) {
            int grow = rowbase + wv * 16 + q * 4 + r;
            if (grow < N) Y[(size_t)grow * H + c * 16 + m] = (f16)acc[c][r];
        }
}

// ======== aggregation: 1 wave/node, 16 lanes x f16x8 per edge, 8 edges in flight ========
// layer0: h = f16( relu(nd*agg + b) * ns )   layer1: out = fp32(nd*agg + b)
__global__ __launch_bounds__(256) void aggC(
    const f16* __restrict__ YA, const int* __restrict__ rpA, const int* __restrict__ esA,
    const float* __restrict__ ndA, const float* __restrict__ nsA, const float* __restrict__ bA,
    float* __restrict__ oA, f16* __restrict__ hA, int nA4, int NA,
    const f16* __restrict__ YB, const int* __restrict__ rpB, const int* __restrict__ esB,
    const float* __restrict__ ndB, const float* __restrict__ nsB, const float* __restrict__ bB,
    float* __restrict__ oB, f16* __restrict__ hB, int NB, int layer0) {
    const f16* Y; const int *rp, *es; const float *nd, *ns, *bias; float* out; f16* hout;
    int N, blk;
    if ((int)blockIdx.x < nA4) {
        Y = YA; rp = rpA; es = esA; nd = ndA; ns = nsA; bias = bA; out = oA; hout = hA;
        N = NA; blk = blockIdx.x;
    } else {
        Y = YB; rp = rpB; es = esB; nd = ndB; ns = nsB; bias = bB; out = oB; hout = hB;
        N = NB; blk = blockIdx.x - nA4;
    }
    int wave = threadIdx.x >> 6;
    int lane = threadIdx.x & 63;
    int node = blk * 4 + wave;
    if (node >= N) return;
    int sub = lane >> 4, d = lane & 15;
    int beg = rp[node], cnt = rp[node + 1] - beg;
    int tot = cnt + 1;                     // +1 virtual self-loop edge
    float acc[8];
#pragma unroll
    for (int i = 0; i < 8; i++) acc[i] = 0.f;
    int j = sub;
    for (; j + 4 < tot; j += 8) {
        int s0 = (j < cnt) ? es[beg + j] : node;
        int s1 = (j + 4 < cnt) ? es[beg + j + 4] : node;
        f16x8 v0 = *(const f16x8*)(Y + (size_t)s0 * H + d * 8);
        f16x8 v1 = *(const f16x8*)(Y + (size_t)s1 * H + d * 8);
#pragma unroll
        for (int i = 0; i < 8; i++) acc[i] += (float)v0[i] + (float)v1[i];
    }
    if (j < tot) {
        int s0 = (j < cnt) ? es[beg + j] : node;
        f16x8 v0 = *(const f16x8*)(Y + (size_t)s0 * H + d * 8);
#pragma unroll
        for (int i = 0; i < 8; i++) acc[i] += (float)v0[i];
    }
#pragma unroll
    for (int i = 0; i < 8; i++) {
        acc[i] += __shfl_xor(acc[i], 16);
        acc[i] += __shfl_xor(acc[i], 32);
    }
    if (lane < 16) {
        float ndv = nd[node];
        float4 b0 = *(const float4*)(bias + d * 8);
        float4 b1 = *(const float4*)(bias + d * 8 + 4);
        float o0 = fmaf(acc[0], ndv, b0.x), o1 = fmaf(acc[1], ndv, b0.y);
        float o2 = fmaf(acc[2], ndv, b0.z), o3 = fmaf(acc[3], ndv, b0.w);
        float o4 = fmaf(acc[4], ndv, b1.x), o5 = fmaf(acc[5], ndv, b1.y);
        float o6 = fmaf(acc[6], ndv, b1.z), o7 = fmaf(acc[7], ndv, b1.w);
        if (layer0) {
            float nsv = ns[node];
            f16x8 hv;
            hv[0] = (f16)(fmaxf(o0, 0.f) * nsv); hv[1] = (f16)(fmaxf(o1, 0.f) * nsv);
            hv[2] = (f16)(fmaxf(o2, 0.f) * nsv); hv[3] = (f16)(fmaxf(o3, 0.f) * nsv);
            hv[4] = (f16)(fmaxf(o4, 0.f) * nsv); hv[5] = (f16)(fmaxf(o5, 0.f) * nsv);
            hv[6] = (f16)(fmaxf(o6, 0.f) * nsv); hv[7] = (f16)(fmaxf(o7, 0.f) * nsv);
            *(f16x8*)(hout + (size_t)node * H + d * 8) = hv;
        } else {
            float* op = out + (size_t)node * H + d * 8;
            *(float4*)op = make_float4(o0, o1, o2, o3);
            *(float4*)(op + 4) = make_float4(o4, o5, o6, o7);
        }
    }
}

// ---------------- host ----------------

struct TypeBufs {
    int *rowptr, *esrc;
    float *norm_s, *norm_d;
    f16 *h, *y, *wt0, *wt1;
};

extern "C" void kernel_launch(void* const* d_in, const int* in_sizes, int n_in,
                              void* d_out, int out_size, void* d_ws, size_t ws_size,
                              hipStream_t stream) {
    (void)n_in; (void)out_size; (void)ws_size;
    const float* feat_a = (const float*)d_in[0];
    const float* feat_b = (const float*)d_in[1];
    const int* src_a = (const int*)d_in[2];
    const int* dst_a = (const int*)d_in[3];
    const int* src_b = (const int*)d_in[4];
    const int* dst_b = (const int*)d_in[5];
    const float* Wa0 = (const float*)d_in[6];
    const float* ba0 = (const float*)d_in[7];
    const float* Wa1 = (const float*)d_in[8];
    const float* ba1 = (const float*)d_in[9];
    const float* Wb0 = (const float*)d_in[10];
    const float* bb0 = (const float*)d_in[11];
    const float* Wb1 = (const float*)d_in[12];
    const float* bb1 = (const float*)d_in[13];

    const int DA = in_sizes[6] / H;   // 256
    const int DB = in_sizes[10] / H;  // 128
    const int NA = in_sizes[0] / DA;  // 50000
    const int NB = in_sizes[1] / DB;  // 30000
    const int EA = in_sizes[2];       // 600000
    const int EB = in_sizes[4];       // 300000

    const int nblkA = ceil_div(EA, EPB), nblkB = ceil_div(EB, EPB);
    const int nbinsA = ceil_div(NA, BUCK), nbinsB = ceil_div(NB, BUCK);
    const int LAd = nbinsA * nblkA, LBd = nbinsB * nblkB;
    const int offAd = 0;
    const int offBd = LAd;
    const int offAs = offBd + LBd;
    const int offBs = offAs + LAd;
    const int Lall = offBs + LBd;

    char* w = (char*)d_ws;
    auto carve = [&](size_t bytes) {
        void* p = (void*)w;
        w += (bytes + 255) & ~(size_t)255;
        return p;
    };
    int* ch = (int*)carve(((size_t)Lall + 1) * 4);
    int* bsum = (int*)carve(256 * 4);
    u32* binned = (u32*)carve((size_t)2 * (EA + EB) * 4);
    auto carve_type = [&](int N, int E, int D) {
        TypeBufs tb;
        tb.rowptr = (int*)carve(((size_t)N + 1) * 4);
        tb.esrc   = (int*)carve((size_t)E * 4);
        tb.norm_s = (float*)carve((size_t)N * 4);
        tb.norm_d = (float*)carve((size_t)N * 4);
        tb.h      = (f16*)carve((size_t)N * H * 2);
        tb.y      = (f16*)carve((size_t)N * H * 2);
        tb.wt0    = (f16*)carve((size_t)D * H * 2);
        tb.wt1    = (f16*)carve((size_t)H * H * 2);
        return tb;
    };
    TypeBufs A = carve_type(NA, EA, DA);
    TypeBufs B = carve_type(NB, EB, DB);

    float* out_a = (float*)d_out;
    float* out_b = out_a + (size_t)NA * H;

    const int gblkA = ceil_div(NA, 64), gblkB = ceil_div(NB, 64);
    const int nA4 = ceil_div(NA, 4), nB4 = ceil_div(NB, 4);
    const int wcBlocks = (DA + 3 * H) / 2;
    const int nScan = Lall + 1;
    const int sb1 = ceil_div(nScan, 1024);

    // ---- prep: 6 launches, all wide-parallel, no device-scope atomics ----
    p1K<<<nblkA + nblkB + wcBlocks, 256, 0, stream>>>(
        src_a, dst_a, EA, nblkA, nbinsA, src_b, dst_b, EB, nblkB, nbinsB,
        ch, offAd, offBd, offAs, offBs, Lall,
        Wa0, A.wt0, Wa1, A.wt1, Wb0, B.wt0, Wb1, B.wt1, DA);
    scan1K<<<sb1, 256, 0, stream>>>(ch, nScan, bsum);
    scan2K<<<1, 256, 0, stream>>>(bsum, sb1);
    scan3K<<<ceil_div(nScan, 256), 256, 0, stream>>>(ch, bsum, nScan);
    p3K<<<nblkA + nblkB, 256, 0, stream>>>(
        src_a, dst_a, EA, nblkA, nbinsA, src_b, dst_b, EB, nblkB, nbinsB,
        ch, offAd, offBd, offAs, offBs, binned);
    p4K<<<2 * (nbinsA + nbinsB), 256, 0, stream>>>(
        binned, ch, nbinsA, nblkA, offAd, offAs, nbinsB, nblkB, offBd, offBs,
        A.rowptr, A.norm_d, A.esrc, NA, EA,
        B.rowptr, B.norm_d, B.esrc, NB, EB,
        A.norm_s, B.norm_s);
    // ---- layer 0 ----
    gemmF<<<gblkA + gblkB, 256, 0, stream>>>(
        feat_a, (const f16*)nullptr, A.wt0, A.norm_s, A.y, NA, DA, gblkA,
        feat_b, (const f16*)nullptr, B.wt0, B.norm_s, B.y, NB, DB, 0);
    aggC<<<nA4 + nB4, 256, 0, stream>>>(
        A.y, A.rowptr, A.esrc, A.norm_d, A.norm_s, ba0, out_a, A.h, nA4, NA,
        B.y, B.rowptr, B.esrc, B.norm_d, B.norm_s, bb0, out_b, B.h, NB, 1);
    // ---- layer 1 ----
    gemmF<<<gblkA + gblkB, 256, 0, stream>>>(
        (const float*)nullptr, A.h, A.wt1, A.norm_s, A.y, NA, H, gblkA,
        (const float*)nullptr, B.h, B.wt1, B.norm_s, B.y, NB, H, 1);
    aggC<<<nA4 + nB4, 256, 0, stream>>>(
        A.y, A.rowptr, A.esrc, A.norm_d, A.norm_s, ba1, out_a, A.h, nA4, NA,
        B.y, B.rowptr, B.esrc, B.norm_d, B.norm_s, bb1, out_b, B.h, NB, 0);
}